// Round 4
// baseline (952.004 us; speedup 1.0000x reference)
//
#include <hip/hip_runtime.h>
#include <hip/hip_bf16.h>

#define D_ 256
#define NH_ 8
#define HD_ 32
#define NL_ 4
#define NP_ 4
#define DFF_ 1024
#define BS_ 8
#define LQ_ 300
#define LV_ 20197
#define NQ_ (BS_*LQ_)          // 2400

__device__ __forceinline__ float u2f(unsigned int u) {
    union { unsigned int i; float f; } v; v.i = u << 16; return v.f;
}
__device__ __forceinline__ unsigned short f2bf_bits(float f) {
    __hip_bfloat16 b = __float2bfloat16(f);
    union { __hip_bfloat16 b; unsigned short u; } v; v.b = b; return v.u;
}

// acc += dot(w4[c], a4[c]) over 4 floats
#define DOT4(accum, wv, ap) do { \
    float4 _a = *(const float4*)(ap); \
    accum += wv.x*_a.x + wv.y*_a.y + wv.z*_a.z + wv.w*_a.w; } while(0)

__device__ __forceinline__ float block_sum256(float v, volatile float* red) {
#pragma unroll
    for (int off = 32; off; off >>= 1) v += __shfl_xor(v, off);
    __syncthreads();
    if ((threadIdx.x & 63) == 0) red[threadIdx.x >> 6] = v;
    __syncthreads();
    return red[0] + red[1] + red[2] + red[3];
}

// ---------------- 1. QKV projection (fused tgt+query_pos) ----------------
__global__ __launch_bounds__(256) void qkv_kernel(
    const float* __restrict__ tgt, const float* __restrict__ qp,
    const float* __restrict__ w, const float* __restrict__ bias,
    float* __restrict__ qh, float* __restrict__ kh, float* __restrict__ vh)
{
    __shared__ float a_qk[8][D_];
    __shared__ float a_t[8][D_];
    const int t = threadIdx.x, m0 = blockIdx.x * 8;
    for (int r = 0; r < 8; ++r) {
        float tv = tgt[(m0+r)*D_ + t];
        float pv = qp[(m0+r)*D_ + t];
        a_t[r][t] = tv; a_qk[r][t] = tv + pv;
    }
    __syncthreads();
    for (int pass = 0; pass < 3; ++pass) {
        const float4* w4 = (const float4*)(w + (pass*256 + t)*D_);
        float (*arow)[D_] = (pass == 2) ? a_t : a_qk;
        float acc[8] = {0,0,0,0,0,0,0,0};
        for (int c = 0; c < 64; ++c) {
            float4 wv = w4[c];
#pragma unroll
            for (int r = 0; r < 8; ++r) DOT4(acc[r], wv, &arow[r][c*4]);
        }
        float bb = bias[pass*256 + t];
        float* dst = (pass == 0) ? qh : (pass == 1) ? kh : vh;
        for (int r = 0; r < 8; ++r) dst[(m0+r)*D_ + t] = acc[r] + bb;
    }
}

// ---------------- 2. Self attention (bf16 K/V tiles in LDS, ~46KB) ----------------
__global__ __launch_bounds__(256) void attn_kernel(
    const float* __restrict__ qh, const float* __restrict__ kh,
    const float* __restrict__ vh, float* __restrict__ sa)
{
    __shared__ unsigned short khl[LQ_][HD_+2];
    __shared__ unsigned short vhl[LQ_][HD_+2];
    __shared__ float sc[4][LQ_];
    __shared__ float qbuf[4][HD_];
    const int b = blockIdx.x >> 3, h = blockIdx.x & 7, chunk = blockIdx.y;
    const int t = threadIdx.x, w = t >> 6, lane = t & 63;
    for (int i = t; i < LQ_*HD_; i += 256) {
        int kq = i >> 5, d = i & 31;
        khl[kq][d] = f2bf_bits(kh[(b*LQ_ + kq)*D_ + h*HD_ + d]);
        vhl[kq][d] = f2bf_bits(vh[(b*LQ_ + kq)*D_ + h*HD_ + d]);
    }
    __syncthreads();
    const float scale = 0.17677669529663687f;  // 1/sqrt(32)
    for (int qi = 0; qi < 15; ++qi) {
        const int q = chunk*60 + w*15 + qi;
        if (lane < HD_) qbuf[w][lane] = qh[(b*LQ_ + q)*D_ + h*HD_ + lane];
        __syncthreads();
        float qv[HD_];
#pragma unroll
        for (int d2 = 0; d2 < HD_; ++d2) qv[d2] = qbuf[w][d2];
        float mx = -1e30f;
        for (int k = lane; k < LQ_; k += 64) {
            float s = 0.f;
#pragma unroll
            for (int d2 = 0; d2 < HD_; ++d2) s += qv[d2]*u2f(khl[k][d2]);
            s *= scale;
            sc[w][k] = s;
            mx = fmaxf(mx, s);
        }
#pragma unroll
        for (int off = 32; off; off >>= 1) mx = fmaxf(mx, __shfl_xor(mx, off));
        float lsum = 0.f;
        for (int k = lane; k < LQ_; k += 64) {
            float e = __expf(sc[w][k] - mx);
            sc[w][k] = e; lsum += e;
        }
#pragma unroll
        for (int off = 32; off; off >>= 1) lsum += __shfl_xor(lsum, off);
        __syncthreads();
        const int d = lane & 31, half = lane >> 5;
        float acc = 0.f;
        for (int k = half*150; k < half*150 + 150; ++k) acc += sc[w][k]*u2f(vhl[k][d]);
        acc += __shfl_down(acc, 32);
        if (lane < 32) sa[(b*LQ_ + q)*D_ + h*HD_ + d] = acc / lsum;
        __syncthreads();
    }
}

// ---------------- 3/6. proj + residual + LayerNorm ----------------
__global__ __launch_bounds__(256) void proj_res_ln_kernel(
    const float* __restrict__ A, const float* __restrict__ W,
    const float* __restrict__ bias, const float* __restrict__ res,
    const float* __restrict__ gw, const float* __restrict__ gb,
    float* __restrict__ out)
{
    __shared__ float arow[8][D_];
    __shared__ float red[4];
    const int t = threadIdx.x, m0 = blockIdx.x * 8;
    for (int r = 0; r < 8; ++r) arow[r][t] = A[(m0+r)*D_ + t];
    __syncthreads();
    float acc[8] = {0,0,0,0,0,0,0,0};
    const float4* w4 = (const float4*)(W + t*D_);
    for (int c = 0; c < 64; ++c) {
        float4 wv = w4[c];
#pragma unroll
        for (int r = 0; r < 8; ++r) DOT4(acc[r], wv, &arow[r][c*4]);
    }
    const float bb = bias[t], gwv = gw[t], gbv = gb[t];
    for (int r = 0; r < 8; ++r) {
        int m = m0 + r;
        float v = acc[r] + bb + res[m*D_+t];
        float mean = block_sum256(v, red) * (1.0f/256.0f);
        float dv = v - mean;
        float var = block_sum256(dv*dv, red) * (1.0f/256.0f);
        out[m*D_+t] = dv * rsqrtf(var + 1e-5f) * gwv + gbv;
    }
}

// ---------------- 4. sampling offsets / attention weights / loc (fp32 out) ----------------
__global__ __launch_bounds__(256) void samp_params_kernel(
    const float* __restrict__ x1, const float* __restrict__ qp,
    const float* __restrict__ so_w, const float* __restrict__ so_b,
    const float* __restrict__ aw_w, const float* __restrict__ aw_b,
    const float* __restrict__ refp,
    float* __restrict__ loc_out, float* __restrict__ aw_out)
{
    __shared__ float qrow[8][D_];
    __shared__ float logits[8][128];
    const int t = threadIdx.x, m0 = blockIdx.x * 8;
    for (int r = 0; r < 8; ++r)
        qrow[r][t] = x1[(m0+r)*D_ + t] + qp[(m0+r)*D_ + t];
    __syncthreads();
    {   // offsets -> loc
        float acc[8] = {0,0,0,0,0,0,0,0};
        const float4* w4 = (const float4*)(so_w + t*D_);
        for (int c = 0; c < 64; ++c) {
            float4 wv = w4[c];
#pragma unroll
            for (int r = 0; r < 8; ++r) DOT4(acc[r], wv, &qrow[r][c*4]);
        }
        const float ob = so_b[t];
        const int c_ = t & 1, l_ = (t >> 3) & 3;
        float nrm;
        if (c_ == 0) nrm = (l_==0)?152.f:(l_==1)?76.f:(l_==2)?38.f:19.f;
        else         nrm = (l_==0)?100.f:(l_==1)?50.f:(l_==2)?25.f:13.f;
        for (int r = 0; r < 8; ++r) {
            int m = m0 + r;
            float off = acc[r] + ob;
            loc_out[m*256 + t] = refp[(m*NL_ + l_)*2 + c_] + off / nrm;
        }
    }
    if (t < 128) {  // attention-weight logits
        float acc[8] = {0,0,0,0,0,0,0,0};
        const float4* w4 = (const float4*)(aw_w + t*D_);
        for (int c = 0; c < 64; ++c) {
            float4 wv = w4[c];
#pragma unroll
            for (int r = 0; r < 8; ++r) DOT4(acc[r], wv, &qrow[r][c*4]);
        }
        const float ab = aw_b[t];
        for (int r = 0; r < 8; ++r) logits[r][t] = acc[r] + ab;
    }
    __syncthreads();
    if (t < 128) {  // softmax over the 16 (l,p) per head
        const int g0 = (t >> 4) << 4;
        for (int r = 0; r < 8; ++r) {
            float mx = -1e30f;
            for (int j = 0; j < 16; ++j) mx = fmaxf(mx, logits[r][g0+j]);
            float s = 0.f;
            for (int j = 0; j < 16; ++j) s += __expf(logits[r][g0+j] - mx);
            aw_out[(m0+r)*128 + t] = __expf(logits[r][t] - mx) / s;
        }
    }
}

// ---------------- 5. fused deformable sampling + value projection ----------------
// Linearity: out[b,q,h,:] = Wv_h @ (sum_{l,p,corner} aw*wgt * src[b,idx,:]) + b_v * sum(aw*wgt)
__global__ __launch_bounds__(256) void samp_fuse_kernel(
    const float* __restrict__ src, const float* __restrict__ Wv,
    const float* __restrict__ vpb,
    const float* __restrict__ loc_f, const float* __restrict__ aw_f,
    float* __restrict__ vo)
{
    __shared__ float svec[NH_][D_];     // aggregated src per head (8KB)
    __shared__ int   cidx[128][4];      // corner row index (-1 = invalid)
    __shared__ float cwt[128][4];       // aw * bilinear weight
    __shared__ float wsum[NH_];
    const int m = blockIdx.x, t = threadIdx.x;
    const int b = m / LQ_;

    if (t < 128) {   // t = h*16 + l*4 + p
        const int l = (t >> 2) & 3;
        const int HS[4] = {100,50,25,13}, WS[4] = {152,76,38,19}, S0[4] = {0,15200,19000,19950};
        const int Hh = HS[l], Ww = WS[l], s0 = S0[l];
        const float aw = aw_f[m*128 + t];
        const float x = loc_f[m*256 + 2*t]*Ww - 0.5f;
        const float y = loc_f[m*256 + 2*t + 1]*Hh - 0.5f;
        const float x0f = floorf(x), y0f = floorf(y);
        const int x0 = (int)x0f, y0 = (int)y0f;
        const float fx = x - x0f, fy = y - y0f;
        const int   cx[4] = {x0, x0+1, x0,   x0+1};
        const int   cy[4] = {y0, y0,   y0+1, y0+1};
        const float cw[4] = {(1.f-fx)*(1.f-fy), fx*(1.f-fy), (1.f-fx)*fy, fx*fy};
        float sw = 0.f;
#pragma unroll
        for (int j = 0; j < 4; ++j) {
            const bool valid = (cx[j] >= 0) & (cx[j] < Ww) & (cy[j] >= 0) & (cy[j] < Hh);
            cidx[t][j] = valid ? (s0 + cy[j]*Ww + cx[j]) : -1;
            float wv = valid ? aw*cw[j] : 0.f;
            cwt[t][j] = wv;
            sw += wv;
        }
#pragma unroll
        for (int off = 8; off; off >>= 1) sw += __shfl_xor(sw, off);
        if ((t & 15) == 0) wsum[t >> 4] = sw;
    }
    __syncthreads();

    const float* sb = src + (size_t)b*LV_*D_;
    float acc[NH_];
#pragma unroll
    for (int h = 0; h < NH_; ++h) acc[h] = 0.f;
#pragma unroll
    for (int h = 0; h < NH_; ++h) {
        for (int j = 0; j < 64; ++j) {
            const int idx = cidx[h*16 + (j >> 2)][j & 3];
            if (idx >= 0) {
                const float wt = cwt[h*16 + (j >> 2)][j & 3];
                acc[h] += wt * sb[idx*D_ + t];
            }
        }
    }
#pragma unroll
    for (int h = 0; h < NH_; ++h) svec[h][t] = acc[h];
    __syncthreads();

    // per-head projection: out dim n = t, head h = t>>5
    const int h = t >> 5;
    const float4* w4 = (const float4*)(Wv + t*D_);
    float a = 0.f;
    for (int c = 0; c < 64; ++c) {
        float4 wv = w4[c];
        DOT4(a, wv, &svec[h][c*4]);
    }
    vo[m*D_ + t] = a + vpb[t]*wsum[h];
}

// ---------------- 7. FFN layer 1 (relu) ----------------
__global__ __launch_bounds__(256) void ffn1_kernel(
    const float* __restrict__ x2, const float* __restrict__ W1,
    const float* __restrict__ b1, float* __restrict__ hid)
{
    __shared__ float arow[8][D_];
    const int t = threadIdx.x, m0 = blockIdx.x * 8;
    for (int r = 0; r < 8; ++r) arow[r][t] = x2[(m0+r)*D_ + t];
    __syncthreads();
    for (int cc = 0; cc < 4; ++cc) {
        const int j = cc*256 + t;
        float acc[8] = {0,0,0,0,0,0,0,0};
        const float4* w4 = (const float4*)(W1 + j*D_);
        for (int c = 0; c < 64; ++c) {
            float4 wv = w4[c];
#pragma unroll
            for (int r = 0; r < 8; ++r) DOT4(acc[r], wv, &arow[r][c*4]);
        }
        const float bb = b1[j];
        for (int r = 0; r < 8; ++r) {
            float v = acc[r] + bb;
            hid[(m0+r)*DFF_ + j] = v > 0.f ? v : 0.f;
        }
    }
}

// ---------------- 8. FFN layer 2 + residual + LN -> fp32 out ----------------
__global__ __launch_bounds__(256) void ffn2_ln_kernel(
    const float* __restrict__ hid, const float* __restrict__ W2,
    const float* __restrict__ b2, const float* __restrict__ res,
    const float* __restrict__ gw, const float* __restrict__ gb,
    float* __restrict__ out)
{
    __shared__ float hrow[8][DFF_];
    __shared__ float red[4];
    const int t = threadIdx.x, m0 = blockIdx.x * 8;
    for (int i = t; i < 8*DFF_; i += 256)
        hrow[i >> 10][i & 1023] = hid[(m0 + (i >> 10))*DFF_ + (i & 1023)];
    __syncthreads();
    float acc[8] = {0,0,0,0,0,0,0,0};
    const float4* w4 = (const float4*)(W2 + t*DFF_);
    for (int c = 0; c < 256; ++c) {
        float4 wv = w4[c];
#pragma unroll
        for (int r = 0; r < 8; ++r) DOT4(acc[r], wv, &hrow[r][c*4]);
    }
    const float bb = b2[t], gwv = gw[t], gbv = gb[t];
    for (int r = 0; r < 8; ++r) {
        int m = m0 + r;
        float v = acc[r] + bb + res[m*D_+t];
        float mean = block_sum256(v, red) * (1.0f/256.0f);
        float dv = v - mean;
        float var = block_sum256(dv*dv, red) * (1.0f/256.0f);
        out[m*D_+t] = dv * rsqrtf(var + 1e-5f) * gwv + gbv;
    }
}

extern "C" void kernel_launch(void* const* d_in, const int* in_sizes, int n_in,
                              void* d_out, int out_size, void* d_ws, size_t ws_size,
                              hipStream_t stream) {
    (void)in_sizes; (void)n_in; (void)out_size; (void)ws_size;
    const float* tgt  = (const float*)d_in[0];
    const float* qpos = (const float*)d_in[1];
    const float* refp = (const float*)d_in[2];
    const float* srcp = (const float*)d_in[3];
    const float* ipw  = (const float*)d_in[4];
    const float* ipb  = (const float*)d_in[5];
    const float* opw  = (const float*)d_in[6];
    const float* opb  = (const float*)d_in[7];
    const float* sow  = (const float*)d_in[8];
    const float* sob  = (const float*)d_in[9];
    const float* aww  = (const float*)d_in[10];
    const float* awb  = (const float*)d_in[11];
    const float* vpw  = (const float*)d_in[12];
    const float* vpb  = (const float*)d_in[13];
    const float* outw = (const float*)d_in[14];
    const float* outb = (const float*)d_in[15];
    const float* l1w  = (const float*)d_in[16];
    const float* l1b  = (const float*)d_in[17];
    const float* l2w  = (const float*)d_in[18];
    const float* l2b  = (const float*)d_in[19];
    const float* n1w  = (const float*)d_in[20];
    const float* n1b  = (const float*)d_in[21];
    const float* n2w  = (const float*)d_in[22];
    const float* n2b  = (const float*)d_in[23];
    const float* n3w  = (const float*)d_in[24];
    const float* n3b  = (const float*)d_in[25];

    float* wsf = (float*)d_ws;
    float* qh   = wsf;
    float* kh   = wsf + 614400;
    float* vh   = wsf + 1228800;
    float* sa   = wsf + 1843200;
    float* x1   = wsf + 2457600;
    float* vo   = wsf + 3072000;
    float* x2   = wsf + 3686400;
    float* hid  = wsf + 4300800;   // ..6758400 floats = 27.0 MB total

    float* xout   = (float*)d_out;            // x   (8,300,256)
    float* locout = xout + 614400;            // loc (8,300,8,4,4,2)
    float* awout  = xout + 1228800;           // aw  (8,300,8,4,4)

    qkv_kernel<<<NQ_/8, 256, 0, stream>>>(tgt, qpos, ipw, ipb, qh, kh, vh);
    attn_kernel<<<dim3(BS_*NH_, 5), 256, 0, stream>>>(qh, kh, vh, sa);
    proj_res_ln_kernel<<<NQ_/8, 256, 0, stream>>>(sa, opw, opb, tgt, n2w, n2b, x1);
    samp_params_kernel<<<NQ_/8, 256, 0, stream>>>(x1, qpos, sow, sob, aww, awb, refp,
                                                  locout, awout);
    samp_fuse_kernel<<<NQ_, 256, 0, stream>>>(srcp, vpw, vpb, locout, awout, vo);
    proj_res_ln_kernel<<<NQ_/8, 256, 0, stream>>>(vo, outw, outb, x1, n1w, n1b, x2);
    ffn1_kernel<<<NQ_/8, 256, 0, stream>>>(x2, l1w, l1b, hid);
    ffn2_ln_kernel<<<NQ_/8, 256, 0, stream>>>(hid, l2w, l2b, x2, n3w, n3b, xout);
}

// Round 5
// 745.041 us; speedup vs baseline: 1.2778x; 1.2778x over previous
//
#include <hip/hip_runtime.h>
#include <hip/hip_bf16.h>

#define D_ 256
#define NH_ 8
#define HD_ 32
#define NL_ 4
#define NP_ 4
#define DFF_ 1024
#define BS_ 8
#define LQ_ 300
#define LV_ 20197
#define NQ_ (BS_*LQ_)          // 2400

__device__ __forceinline__ float u2f(unsigned int u) {
    union { unsigned int i; float f; } v; v.i = u << 16; return v.f;
}
__device__ __forceinline__ unsigned short f2bf_bits(float f) {
    __hip_bfloat16 b = __float2bfloat16(f);
    union { __hip_bfloat16 b; unsigned short u; } v; v.b = b; return v.u;
}

// acc += dot(w4[c], a4[c]) over 4 floats
#define DOT4(accum, wv, ap) do { \
    float4 _a = *(const float4*)(ap); \
    accum += wv.x*_a.x + wv.y*_a.y + wv.z*_a.z + wv.w*_a.w; } while(0)

__device__ __forceinline__ float block_sum256(float v, volatile float* red) {
#pragma unroll
    for (int off = 32; off; off >>= 1) v += __shfl_xor(v, off);
    __syncthreads();
    if ((threadIdx.x & 63) == 0) red[threadIdx.x >> 6] = v;
    __syncthreads();
    return red[0] + red[1] + red[2] + red[3];
}

// ---------------- 1. QKV projection (fused tgt+query_pos) ----------------
__global__ __launch_bounds__(256) void qkv_kernel(
    const float* __restrict__ tgt, const float* __restrict__ qp,
    const float* __restrict__ w, const float* __restrict__ bias,
    float* __restrict__ qh, float* __restrict__ kh, float* __restrict__ vh)
{
    __shared__ float a_qk[8][D_];
    __shared__ float a_t[8][D_];
    const int t = threadIdx.x, m0 = blockIdx.x * 8;
    for (int r = 0; r < 8; ++r) {
        float tv = tgt[(m0+r)*D_ + t];
        float pv = qp[(m0+r)*D_ + t];
        a_t[r][t] = tv; a_qk[r][t] = tv + pv;
    }
    __syncthreads();
    for (int pass = 0; pass < 3; ++pass) {
        const float4* w4 = (const float4*)(w + (pass*256 + t)*D_);
        float (*arow)[D_] = (pass == 2) ? a_t : a_qk;
        float acc[8] = {0,0,0,0,0,0,0,0};
        for (int c = 0; c < 64; ++c) {
            float4 wv = w4[c];
#pragma unroll
            for (int r = 0; r < 8; ++r) DOT4(acc[r], wv, &arow[r][c*4]);
        }
        float bb = bias[pass*256 + t];
        float* dst = (pass == 0) ? qh : (pass == 1) ? kh : vh;
        for (int r = 0; r < 8; ++r) dst[(m0+r)*D_ + t] = acc[r] + bb;
    }
}

// ---------------- 2. Self attention (bf16 K/V tiles in LDS, ~46KB) ----------------
__global__ __launch_bounds__(256) void attn_kernel(
    const float* __restrict__ qh, const float* __restrict__ kh,
    const float* __restrict__ vh, float* __restrict__ sa)
{
    __shared__ unsigned short khl[LQ_][HD_+2];
    __shared__ unsigned short vhl[LQ_][HD_+2];
    __shared__ float sc[4][LQ_];
    __shared__ float qbuf[4][HD_];
    const int b = blockIdx.x >> 3, h = blockIdx.x & 7, chunk = blockIdx.y;
    const int t = threadIdx.x, w = t >> 6, lane = t & 63;
    for (int i = t; i < LQ_*HD_; i += 256) {
        int kq = i >> 5, d = i & 31;
        khl[kq][d] = f2bf_bits(kh[(b*LQ_ + kq)*D_ + h*HD_ + d]);
        vhl[kq][d] = f2bf_bits(vh[(b*LQ_ + kq)*D_ + h*HD_ + d]);
    }
    __syncthreads();
    const float scale = 0.17677669529663687f;  // 1/sqrt(32)
    for (int qi = 0; qi < 15; ++qi) {
        const int q = chunk*60 + w*15 + qi;
        if (lane < HD_) qbuf[w][lane] = qh[(b*LQ_ + q)*D_ + h*HD_ + lane];
        __syncthreads();
        float qv[HD_];
#pragma unroll
        for (int d2 = 0; d2 < HD_; ++d2) qv[d2] = qbuf[w][d2];
        float mx = -1e30f;
        for (int k = lane; k < LQ_; k += 64) {
            float s = 0.f;
#pragma unroll
            for (int d2 = 0; d2 < HD_; ++d2) s += qv[d2]*u2f(khl[k][d2]);
            s *= scale;
            sc[w][k] = s;
            mx = fmaxf(mx, s);
        }
#pragma unroll
        for (int off = 32; off; off >>= 1) mx = fmaxf(mx, __shfl_xor(mx, off));
        float lsum = 0.f;
        for (int k = lane; k < LQ_; k += 64) {
            float e = __expf(sc[w][k] - mx);
            sc[w][k] = e; lsum += e;
        }
#pragma unroll
        for (int off = 32; off; off >>= 1) lsum += __shfl_xor(lsum, off);
        __syncthreads();
        const int d = lane & 31, half = lane >> 5;
        float acc = 0.f;
        for (int k = half*150; k < half*150 + 150; ++k) acc += sc[w][k]*u2f(vhl[k][d]);
        acc += __shfl_down(acc, 32);
        if (lane < 32) sa[(b*LQ_ + q)*D_ + h*HD_ + d] = acc / lsum;
        __syncthreads();
    }
}

// ---------------- 3/6. proj + residual + LayerNorm ----------------
__global__ __launch_bounds__(256) void proj_res_ln_kernel(
    const float* __restrict__ A, const float* __restrict__ W,
    const float* __restrict__ bias, const float* __restrict__ res,
    const float* __restrict__ gw, const float* __restrict__ gb,
    float* __restrict__ out)
{
    __shared__ float arow[8][D_];
    __shared__ float red[4];
    const int t = threadIdx.x, m0 = blockIdx.x * 8;
    for (int r = 0; r < 8; ++r) arow[r][t] = A[(m0+r)*D_ + t];
    __syncthreads();
    float acc[8] = {0,0,0,0,0,0,0,0};
    const float4* w4 = (const float4*)(W + t*D_);
    for (int c = 0; c < 64; ++c) {
        float4 wv = w4[c];
#pragma unroll
        for (int r = 0; r < 8; ++r) DOT4(acc[r], wv, &arow[r][c*4]);
    }
    const float bb = bias[t], gwv = gw[t], gbv = gb[t];
    for (int r = 0; r < 8; ++r) {
        int m = m0 + r;
        float v = acc[r] + bb + res[m*D_+t];
        float mean = block_sum256(v, red) * (1.0f/256.0f);
        float dv = v - mean;
        float var = block_sum256(dv*dv, red) * (1.0f/256.0f);
        out[m*D_+t] = dv * rsqrtf(var + 1e-5f) * gwv + gbv;
    }
}

// ---------------- 4. sampling offsets / attention weights / loc (fp32 out) ----------------
__global__ __launch_bounds__(256) void samp_params_kernel(
    const float* __restrict__ x1, const float* __restrict__ qp,
    const float* __restrict__ so_w, const float* __restrict__ so_b,
    const float* __restrict__ aw_w, const float* __restrict__ aw_b,
    const float* __restrict__ refp,
    float* __restrict__ loc_out, float* __restrict__ aw_out)
{
    __shared__ float qrow[8][D_];
    __shared__ float logits[8][128];
    const int t = threadIdx.x, m0 = blockIdx.x * 8;
    for (int r = 0; r < 8; ++r)
        qrow[r][t] = x1[(m0+r)*D_ + t] + qp[(m0+r)*D_ + t];
    __syncthreads();
    {   // offsets -> loc
        float acc[8] = {0,0,0,0,0,0,0,0};
        const float4* w4 = (const float4*)(so_w + t*D_);
        for (int c = 0; c < 64; ++c) {
            float4 wv = w4[c];
#pragma unroll
            for (int r = 0; r < 8; ++r) DOT4(acc[r], wv, &qrow[r][c*4]);
        }
        const float ob = so_b[t];
        const int c_ = t & 1, l_ = (t >> 3) & 3;
        float nrm;
        if (c_ == 0) nrm = (l_==0)?152.f:(l_==1)?76.f:(l_==2)?38.f:19.f;
        else         nrm = (l_==0)?100.f:(l_==1)?50.f:(l_==2)?25.f:13.f;
        for (int r = 0; r < 8; ++r) {
            int m = m0 + r;
            float off = acc[r] + ob;
            loc_out[m*256 + t] = refp[(m*NL_ + l_)*2 + c_] + off / nrm;
        }
    }
    if (t < 128) {  // attention-weight logits
        float acc[8] = {0,0,0,0,0,0,0,0};
        const float4* w4 = (const float4*)(aw_w + t*D_);
        for (int c = 0; c < 64; ++c) {
            float4 wv = w4[c];
#pragma unroll
            for (int r = 0; r < 8; ++r) DOT4(acc[r], wv, &qrow[r][c*4]);
        }
        const float ab = aw_b[t];
        for (int r = 0; r < 8; ++r) logits[r][t] = acc[r] + ab;
    }
    __syncthreads();
    if (t < 128) {  // softmax over the 16 (l,p) per head
        const int g0 = (t >> 4) << 4;
        for (int r = 0; r < 8; ++r) {
            float mx = -1e30f;
            for (int j = 0; j < 16; ++j) mx = fmaxf(mx, logits[r][g0+j]);
            float s = 0.f;
            for (int j = 0; j < 16; ++j) s += __expf(logits[r][g0+j] - mx);
            aw_out[(m0+r)*128 + t] = __expf(logits[r][t] - mx) / s;
        }
    }
}

// ---------------- 5. fused deformable sampling + value projection ----------------
// Linearity: out[b,q,h,:] = Wv_h @ (sum_{l,p,corner} aw*wgt * src[b,idx,:]) + b_v * sum(aw*wgt)
// Branchless gather: invalid corners get clamped index + zero weight, so every
// load is unconditional and independent -> deep vmcnt pipelining.
__global__ __launch_bounds__(256) void samp_fuse_kernel(
    const float* __restrict__ src, const float* __restrict__ Wv,
    const float* __restrict__ vpb,
    const float* __restrict__ loc_f, const float* __restrict__ aw_f,
    float* __restrict__ vo)
{
    __shared__ float svec[NH_][D_];     // aggregated src per head (8KB)
    __shared__ int   cidx[128][4];      // clamped corner row index
    __shared__ float cwt[128][4];       // aw * bilinear weight (0 if invalid)
    __shared__ float wsum[NH_];
    const int m = blockIdx.x, t = threadIdx.x;
    const int b = m / LQ_;

    if (t < 128) {   // t = h*16 + l*4 + p
        const int l = (t >> 2) & 3;
        const int HS[4] = {100,50,25,13}, WS[4] = {152,76,38,19}, S0[4] = {0,15200,19000,19950};
        const int Hh = HS[l], Ww = WS[l], s0 = S0[l];
        const float aw = aw_f[m*128 + t];
        const float x = loc_f[m*256 + 2*t]*Ww - 0.5f;
        const float y = loc_f[m*256 + 2*t + 1]*Hh - 0.5f;
        const float x0f = floorf(x), y0f = floorf(y);
        const int x0 = (int)x0f, y0 = (int)y0f;
        const float fx = x - x0f, fy = y - y0f;
        const int   cx[4] = {x0, x0+1, x0,   x0+1};
        const int   cy[4] = {y0, y0,   y0+1, y0+1};
        const float cw[4] = {(1.f-fx)*(1.f-fy), fx*(1.f-fy), (1.f-fx)*fy, fx*fy};
        float sw = 0.f;
#pragma unroll
        for (int j = 0; j < 4; ++j) {
            const bool valid = (cx[j] >= 0) & (cx[j] < Ww) & (cy[j] >= 0) & (cy[j] < Hh);
            cidx[t][j] = valid ? (s0 + cy[j]*Ww + cx[j]) : s0;   // clamped, weight 0
            float wv = valid ? aw*cw[j] : 0.f;
            cwt[t][j] = wv;
            sw += wv;
        }
#pragma unroll
        for (int off = 8; off; off >>= 1) sw += __shfl_xor(sw, off);
        if ((t & 15) == 0) wsum[t >> 4] = sw;
    }
    __syncthreads();

    const float* sb = src + (size_t)b*LV_*D_ + t;
#pragma unroll
    for (int h = 0; h < NH_; ++h) {
        float a0 = 0.f, a1 = 0.f, a2 = 0.f, a3 = 0.f;
#pragma unroll 4
        for (int s = 0; s < 16; ++s) {
            const int base = h*16 + s;
            const int   i0 = cidx[base][0], i1 = cidx[base][1],
                        i2 = cidx[base][2], i3 = cidx[base][3];
            const float w0 = cwt[base][0], w1 = cwt[base][1],
                        w2 = cwt[base][2], w3 = cwt[base][3];
            a0 += w0 * sb[(size_t)i0*D_];
            a1 += w1 * sb[(size_t)i1*D_];
            a2 += w2 * sb[(size_t)i2*D_];
            a3 += w3 * sb[(size_t)i3*D_];
        }
        svec[h][t] = (a0 + a1) + (a2 + a3);
    }
    __syncthreads();

    // per-head projection: out dim n = t, head h = t>>5
    const int h = t >> 5;
    const float4* w4 = (const float4*)(Wv + t*D_);
    float a = 0.f;
    for (int c = 0; c < 64; ++c) {
        float4 wv = w4[c];
        DOT4(a, wv, &svec[h][c*4]);
    }
    vo[m*D_ + t] = a + vpb[t]*wsum[h];
}

// ---------------- 7. FFN layer 1 (relu) ----------------
__global__ __launch_bounds__(256) void ffn1_kernel(
    const float* __restrict__ x2, const float* __restrict__ W1,
    const float* __restrict__ b1, float* __restrict__ hid)
{
    __shared__ float arow[8][D_];
    const int t = threadIdx.x, m0 = blockIdx.x * 8;
    for (int r = 0; r < 8; ++r) arow[r][t] = x2[(m0+r)*D_ + t];
    __syncthreads();
    for (int cc = 0; cc < 4; ++cc) {
        const int j = cc*256 + t;
        float acc[8] = {0,0,0,0,0,0,0,0};
        const float4* w4 = (const float4*)(W1 + j*D_);
        for (int c = 0; c < 64; ++c) {
            float4 wv = w4[c];
#pragma unroll
            for (int r = 0; r < 8; ++r) DOT4(acc[r], wv, &arow[r][c*4]);
        }
        const float bb = b1[j];
        for (int r = 0; r < 8; ++r) {
            float v = acc[r] + bb;
            hid[(m0+r)*DFF_ + j] = v > 0.f ? v : 0.f;
        }
    }
}

// ---------------- 8. FFN layer 2 + residual + LN -> fp32 out ----------------
__global__ __launch_bounds__(256) void ffn2_ln_kernel(
    const float* __restrict__ hid, const float* __restrict__ W2,
    const float* __restrict__ b2, const float* __restrict__ res,
    const float* __restrict__ gw, const float* __restrict__ gb,
    float* __restrict__ out)
{
    __shared__ float hrow[8][DFF_];
    __shared__ float red[4];
    const int t = threadIdx.x, m0 = blockIdx.x * 8;
    for (int i = t; i < 8*DFF_; i += 256)
        hrow[i >> 10][i & 1023] = hid[(m0 + (i >> 10))*DFF_ + (i & 1023)];
    __syncthreads();
    float acc[8] = {0,0,0,0,0,0,0,0};
    const float4* w4 = (const float4*)(W2 + t*DFF_);
    for (int c = 0; c < 256; ++c) {
        float4 wv = w4[c];
#pragma unroll
        for (int r = 0; r < 8; ++r) DOT4(acc[r], wv, &hrow[r][c*4]);
    }
    const float bb = b2[t], gwv = gw[t], gbv = gb[t];
    for (int r = 0; r < 8; ++r) {
        int m = m0 + r;
        float v = acc[r] + bb + res[m*D_+t];
        float mean = block_sum256(v, red) * (1.0f/256.0f);
        float dv = v - mean;
        float var = block_sum256(dv*dv, red) * (1.0f/256.0f);
        out[m*D_+t] = dv * rsqrtf(var + 1e-5f) * gwv + gbv;
    }
}

extern "C" void kernel_launch(void* const* d_in, const int* in_sizes, int n_in,
                              void* d_out, int out_size, void* d_ws, size_t ws_size,
                              hipStream_t stream) {
    (void)in_sizes; (void)n_in; (void)out_size; (void)ws_size;
    const float* tgt  = (const float*)d_in[0];
    const float* qpos = (const float*)d_in[1];
    const float* refp = (const float*)d_in[2];
    const float* srcp = (const float*)d_in[3];
    const float* ipw  = (const float*)d_in[4];
    const float* ipb  = (const float*)d_in[5];
    const float* opw  = (const float*)d_in[6];
    const float* opb  = (const float*)d_in[7];
    const float* sow  = (const float*)d_in[8];
    const float* sob  = (const float*)d_in[9];
    const float* aww  = (const float*)d_in[10];
    const float* awb  = (const float*)d_in[11];
    const float* vpw  = (const float*)d_in[12];
    const float* vpb  = (const float*)d_in[13];
    const float* outw = (const float*)d_in[14];
    const float* outb = (const float*)d_in[15];
    const float* l1w  = (const float*)d_in[16];
    const float* l1b  = (const float*)d_in[17];
    const float* l2w  = (const float*)d_in[18];
    const float* l2b  = (const float*)d_in[19];
    const float* n1w  = (const float*)d_in[20];
    const float* n1b  = (const float*)d_in[21];
    const float* n2w  = (const float*)d_in[22];
    const float* n2b  = (const float*)d_in[23];
    const float* n3w  = (const float*)d_in[24];
    const float* n3b  = (const float*)d_in[25];

    float* wsf = (float*)d_ws;
    float* qh   = wsf;
    float* kh   = wsf + 614400;
    float* vh   = wsf + 1228800;
    float* sa   = wsf + 1843200;
    float* x1   = wsf + 2457600;
    float* vo   = wsf + 3072000;
    float* x2   = wsf + 3686400;
    float* hid  = wsf + 4300800;   // ..6758400 floats = 27.0 MB total

    float* xout   = (float*)d_out;            // x   (8,300,256)
    float* locout = xout + 614400;            // loc (8,300,8,4,4,2)
    float* awout  = xout + 1228800;           // aw  (8,300,8,4,4)

    qkv_kernel<<<NQ_/8, 256, 0, stream>>>(tgt, qpos, ipw, ipb, qh, kh, vh);
    attn_kernel<<<dim3(BS_*NH_, 5), 256, 0, stream>>>(qh, kh, vh, sa);
    proj_res_ln_kernel<<<NQ_/8, 256, 0, stream>>>(sa, opw, opb, tgt, n2w, n2b, x1);
    samp_params_kernel<<<NQ_/8, 256, 0, stream>>>(x1, qpos, sow, sob, aww, awb, refp,
                                                  locout, awout);
    samp_fuse_kernel<<<NQ_, 256, 0, stream>>>(srcp, vpw, vpb, locout, awout, vo);
    proj_res_ln_kernel<<<NQ_/8, 256, 0, stream>>>(vo, outw, outb, x1, n1w, n1b, x2);
    ffn1_kernel<<<NQ_/8, 256, 0, stream>>>(x2, l1w, l1b, hid);
    ffn2_ln_kernel<<<NQ_/8, 256, 0, stream>>>(hid, l2w, l2b, x2, n3w, n3b, xout);
}